// Round 6
// baseline (1394.790 us; speedup 1.0000x reference)
//
#include <hip/hip_runtime.h>

// GCN + low-rank global attention (LRGA), N=100k, E=1.6M, D=128, K=64.
// Inputs fp32 + int32 edge_index; OUTPUT fp32 (reference dtype).
// Intermediates h (x@Wg) and t (relu(x@Wa+ba)) stored bf16 in workspace.
#define DIN   128
#define DOUT  128
#define KR    64
#define TCOLS 256   // 4*K

typedef unsigned short ushort_t;

__device__ __forceinline__ float bf2f(unsigned short u) {
  return __uint_as_float(((unsigned int)u) << 16);
}
__device__ __forceinline__ unsigned short f2bf(float f) {
  unsigned int b = __float_as_uint(f);
  b = b + 0x7FFFu + ((b >> 16) & 1u);
  return (unsigned short)(b >> 16);
}

// ---------------------------------------------------------------- init
__global__ __launch_bounds__(256) void k_init(int* __restrict__ degc, float* __restrict__ VtZ,
                                              float* __restrict__ colsum, int N) {
  int i = blockIdx.x * 256 + threadIdx.x;
  if (i < N) degc[i] = 1;            // self-loop gives deg >= 1
  if (i < 4096) VtZ[i] = 0.f;
  if (i < 128) colsum[i] = 0.f;
}

// ---------------------------------------------------------------- degree (in-degree via dst row)
__global__ __launch_bounds__(256) void k_deg(const int* __restrict__ ei, int* __restrict__ degc, int E) {
  int e = blockIdx.x * 256 + threadIdx.x;
  if (e < E) atomicAdd(&degc[ei[E + e]], 1);
}

// ---------------------------------------------------------------- single-block scan:
// offs = exclusive prefix of (degc-1); offs[N] = E; dinv = rsqrt(degc); cursor = 0.
__global__ __launch_bounds__(1024) void k_scan(const int* __restrict__ degc, int* __restrict__ offs,
                                               float* __restrict__ dinv, int* __restrict__ cursor, int N) {
  __shared__ int s[1024];
  int tid = threadIdx.x;
  int CH = (N + 1023) >> 10;
  int i0 = tid * CH;
  int i1 = min(i0 + CH, N);
  int tsum = 0;
  for (int i = i0; i < i1; ++i) tsum += degc[i] - 1;
  s[tid] = tsum;
  __syncthreads();
  for (int off = 1; off < 1024; off <<= 1) {
    int v = (tid >= off) ? s[tid - off] : 0;
    __syncthreads();
    s[tid] += v;
    __syncthreads();
  }
  int run = s[tid] - tsum;
  for (int i = i0; i < i1; ++i) {
    offs[i] = run;
    run += degc[i] - 1;
    dinv[i] = rsqrtf((float)degc[i]);
    cursor[i] = 0;
  }
  if (tid == 0) offs[N] = s[1023];
}

// ---------------------------------------------------------------- CSR scatter with per-edge norm
__global__ __launch_bounds__(256) void k_scatter(const int* __restrict__ ei, const int* __restrict__ offs,
                                                 int* __restrict__ cursor, const float* __restrict__ dinv,
                                                 int* __restrict__ csr_s, float* __restrict__ csr_n, int E) {
  int e = blockIdx.x * 256 + threadIdx.x;
  if (e < E) {
    int s = ei[e];          // src
    int d = ei[E + e];      // dst
    int pos = atomicAdd(&cursor[d], 1);
    int idx = offs[d] + pos;
    csr_s[idx] = s;
    csr_n[idx] = dinv[s] * dinv[d];
  }
}

// ---------------------------------------------------------------- fused GEMM: h = x@Wg (bf16) ; t = relu(x@Wa + ba) (bf16)
__global__ __launch_bounds__(256) void k_gemm1(const float* __restrict__ x,
                                               const float* __restrict__ Wg,
                                               const float* __restrict__ Wa,
                                               const float* __restrict__ ba,
                                               ushort_t* __restrict__ hs, ushort_t* __restrict__ t, int N) {
  __shared__ float xS[64 * 68];   // [row][k] stride 68
  __shared__ float wS[64 * 68];   // [k][col] stride 68
  int tid = threadIdx.x;
  int row0 = blockIdx.y * 64;
  int cbase = blockIdx.x * 64;
  int tc = tid & 15, tr = tid >> 4;
  float acc[4][4] = {};
  for (int kc = 0; kc < 2; ++kc) {
    for (int idx = tid; idx < 64 * 16; idx += 256) {
      int r = idx >> 4, c4 = idx & 15;
      int row = row0 + r;
      float4 v = (row < N) ? *(const float4*)&x[(size_t)row * DIN + kc * 64 + c4 * 4]
                           : make_float4(0.f, 0.f, 0.f, 0.f);
      *(float4*)&xS[r * 68 + c4 * 4] = v;
    }
    if (cbase < DOUT) {
      for (int idx = tid; idx < 64 * 16; idx += 256) {
        int k = idx >> 4, c4 = idx & 15;
        float4 v = *(const float4*)&Wg[(size_t)(kc * 64 + k) * DOUT + cbase + c4 * 4];
        *(float4*)&wS[k * 68 + c4 * 4] = v;
      }
    } else {
      for (int idx = tid; idx < 64 * 16; idx += 256) {
        int k = idx >> 4, c4 = idx & 15;
        float4 v = *(const float4*)&Wa[(size_t)(kc * 64 + k) * TCOLS + (cbase - DOUT) + c4 * 4];
        *(float4*)&wS[k * 68 + c4 * 4] = v;
      }
    }
    __syncthreads();
#pragma unroll
    for (int kv = 0; kv < 16; ++kv) {
      float xv[4][4], wv[4][4];
#pragma unroll
      for (int i = 0; i < 4; ++i) {
        float4 v = *(const float4*)&xS[(tr * 4 + i) * 68 + kv * 4];
        xv[i][0] = v.x; xv[i][1] = v.y; xv[i][2] = v.z; xv[i][3] = v.w;
      }
#pragma unroll
      for (int kk = 0; kk < 4; ++kk) {
        float4 v = *(const float4*)&wS[(kv * 4 + kk) * 68 + tc * 4];
        wv[kk][0] = v.x; wv[kk][1] = v.y; wv[kk][2] = v.z; wv[kk][3] = v.w;
      }
#pragma unroll
      for (int i = 0; i < 4; ++i)
#pragma unroll
        for (int kk = 0; kk < 4; ++kk) {
          acc[i][0] += xv[i][kk] * wv[kk][0];
          acc[i][1] += xv[i][kk] * wv[kk][1];
          acc[i][2] += xv[i][kk] * wv[kk][2];
          acc[i][3] += xv[i][kk] * wv[kk][3];
        }
    }
    __syncthreads();
  }
  int gc0 = cbase + tc * 4;
  if (gc0 < DOUT) {
#pragma unroll
    for (int i = 0; i < 4; ++i) {
      int row = row0 + tr * 4 + i;
      if (row < N) {
        ushort4 o;
        o.x = f2bf(acc[i][0]); o.y = f2bf(acc[i][1]);
        o.z = f2bf(acc[i][2]); o.w = f2bf(acc[i][3]);
        *(ushort4*)&hs[(size_t)row * DOUT + gc0] = o;
      }
    }
  } else {
    int ca0 = gc0 - DOUT;
    float bav[4];
#pragma unroll
    for (int q = 0; q < 4; ++q) bav[q] = ba[ca0 + q];
#pragma unroll
    for (int i = 0; i < 4; ++i) {
      int row = row0 + tr * 4 + i;
      if (row < N) {
        ushort4 o;
        o.x = f2bf(fmaxf(acc[i][0] + bav[0], 0.f));
        o.y = f2bf(fmaxf(acc[i][1] + bav[1], 0.f));
        o.z = f2bf(fmaxf(acc[i][2] + bav[2], 0.f));
        o.w = f2bf(fmaxf(acc[i][3] + bav[3], 0.f));
        *(ushort4*)&t[(size_t)row * TCOLS + ca0] = o;
      }
    }
  }
}

// ---------------------------------------------------------------- VtZ (64x64) + colsum(U),colsum(V)
__global__ __launch_bounds__(256) void k_red(const ushort_t* __restrict__ t, float* __restrict__ VtZ,
                                             float* __restrict__ colsum, int N) {
  __shared__ float uvz[16 * 192];   // cols 0..191 of t (U,V,Z)
  int tid = threadIdx.x;
  int RB = (N + gridDim.x - 1) / gridDim.x;
  int row0 = blockIdx.x * RB;
  int rowend = min(row0 + RB, N);
  int k = tid >> 2;
  int l0 = (tid & 3) * 16;
  float acc[16] = {};
  float cs = 0.f;
  for (int r0 = row0; r0 < rowend; r0 += 16) {
    for (int idx = tid; idx < 16 * 48; idx += 256) {
      int r = idx / 48, c4 = idx - r * 48;
      int row = r0 + r;
      float4 f;
      if (row < rowend) {
        ushort4 u = ((const ushort4*)&t[(size_t)row * TCOLS])[c4];
        f = make_float4(bf2f(u.x), bf2f(u.y), bf2f(u.z), bf2f(u.w));
      } else {
        f = make_float4(0.f, 0.f, 0.f, 0.f);
      }
      *(float4*)&uvz[r * 192 + c4 * 4] = f;
    }
    __syncthreads();
#pragma unroll
    for (int r = 0; r < 16; ++r) {
      float vk = uvz[r * 192 + 64 + k];
      const float4* zp = (const float4*)&uvz[r * 192 + 128 + l0];
#pragma unroll
      for (int q = 0; q < 4; ++q) {
        float4 z = zp[q];
        acc[q * 4 + 0] += vk * z.x;
        acc[q * 4 + 1] += vk * z.y;
        acc[q * 4 + 2] += vk * z.z;
        acc[q * 4 + 3] += vk * z.w;
      }
    }
    if (tid < 128) {
#pragma unroll
      for (int r = 0; r < 16; ++r) cs += uvz[r * 192 + tid];
    }
    __syncthreads();
  }
#pragma unroll
  for (int q = 0; q < 16; ++q) atomicAdd(&VtZ[k * 64 + l0 + q], acc[q]);
  if (tid < 128) atomicAdd(&colsum[tid], cs);
}

// ---------------------------------------------------------------- D = N / dot(colsumU, colsumV)
__global__ __launch_bounds__(64) void k_d(const float* __restrict__ colsum, float* __restrict__ Dws, int N) {
  __shared__ float s[64];
  int k = threadIdx.x;
  s[k] = colsum[k] * colsum[64 + k];
  __syncthreads();
  for (int off = 32; off > 0; off >>= 1) {
    if (k < off) s[k] += s[k + off];
    __syncthreads();
  }
  if (k == 0) {
    float p = s[0];
    Dws[0] = (p != 0.f) ? ((float)N / p) : 0.f;
  }
}

// ---------------------------------------------------------------- fused: gather-aggregate + relu, res=U@VtZ*D, T, then @W_red
// OUTPUT IS FP32.
__global__ __launch_bounds__(256) void k_final(const ushort_t* __restrict__ hs, const ushort_t* __restrict__ t,
                                               const int* __restrict__ offs, const int* __restrict__ csr_s,
                                               const float* __restrict__ csr_n,
                                               const float* __restrict__ dinv,
                                               const float* __restrict__ VtZg, const float* __restrict__ Dws,
                                               const float* __restrict__ bg,
                                               const float* __restrict__ Wr,
                                               const float* __restrict__ br,
                                               float* __restrict__ out, int N) {
  __shared__ float yS[32 * 260];    // [node][256 + pad]
  __shared__ float vtzS[4096];
  int tid = threadIdx.x;
  for (int idx = tid; idx < 4096; idx += 256) vtzS[idx] = VtZg[idx];
  for (int idx = tid; idx < 32 * 260; idx += 256) yS[idx] = 0.f;
  __syncthreads();
  int lane = tid & 63;
  int wave = tid >> 6;
  float Dv = Dws[0];
  int nb = blockIdx.x * 32;
  int c2 = 2 * lane;
  float bg0 = bg[c2], bg1 = bg[c2 + 1];
  for (int p = 0; p < 8; ++p) {
    int ln = wave * 8 + p;
    int node = nb + ln;
    if (node < N) {
      float dn = dinv[node];
      float a0, a1;
      {
        ushort2 u = *(const ushort2*)&hs[(size_t)node * DOUT + c2];
        a0 = dn * dn * bf2f(u.x); a1 = dn * dn * bf2f(u.y);   // self-loop term
      }
      int e0 = offs[node], e1 = offs[node + 1];
      for (int e = e0; e < e1; ++e) {
        int s = csr_s[e];
        float nrm = csr_n[e];
        ushort2 u = *(const ushort2*)&hs[(size_t)s * DOUT + c2];
        a0 += nrm * bf2f(u.x); a1 += nrm * bf2f(u.y);
      }
      yS[ln * 260 + c2]     = fmaxf(a0 + bg0, 0.f);
      yS[ln * 260 + c2 + 1] = fmaxf(a1 + bg1, 0.f);
      const ushort_t* Urow = &t[(size_t)node * TCOLS];
      float r = 0.f;
#pragma unroll 16
      for (int k = 0; k < 64; ++k) r += bf2f(Urow[k]) * vtzS[k * 64 + lane];
      yS[ln * 260 + 128 + lane] = r * Dv;
      yS[ln * 260 + 192 + lane] = bf2f(Urow[192 + lane]);
    }
  }
  __syncthreads();
  // phase B: out[32 x 128] = y[32 x 256] @ W_red[256 x 128] + b_red  (fp32 out)
  int tc = tid & 31, tr = tid >> 5;
  int c0 = tc * 4, m0 = tr * 4;
  float brv[4];
#pragma unroll
  for (int q = 0; q < 4; ++q) brv[q] = br[c0 + q];
  float acc2[4][4] = {};
  for (int qc = 0; qc < 64; ++qc) {
    float yv[4][4], wv[4][4];
#pragma unroll
    for (int i = 0; i < 4; ++i) {
      float4 v = *(const float4*)&yS[(m0 + i) * 260 + qc * 4];
      yv[i][0] = v.x; yv[i][1] = v.y; yv[i][2] = v.z; yv[i][3] = v.w;
    }
#pragma unroll
    for (int kk = 0; kk < 4; ++kk) {
      float4 v = *(const float4*)&Wr[(size_t)(qc * 4 + kk) * DOUT + c0];
      wv[kk][0] = v.x; wv[kk][1] = v.y; wv[kk][2] = v.z; wv[kk][3] = v.w;
    }
#pragma unroll
    for (int i = 0; i < 4; ++i)
#pragma unroll
      for (int kk = 0; kk < 4; ++kk) {
        acc2[i][0] += yv[i][kk] * wv[kk][0];
        acc2[i][1] += yv[i][kk] * wv[kk][1];
        acc2[i][2] += yv[i][kk] * wv[kk][2];
        acc2[i][3] += yv[i][kk] * wv[kk][3];
      }
  }
#pragma unroll
  for (int i = 0; i < 4; ++i) {
    int node = nb + m0 + i;
    if (node < N) {
      float4 o = make_float4(acc2[i][0] + brv[0], acc2[i][1] + brv[1],
                             acc2[i][2] + brv[2], acc2[i][3] + brv[3]);
      *(float4*)&out[(size_t)node * DOUT + c0] = o;
    }
  }
}

// ---------------------------------------------------------------- launch
extern "C" void kernel_launch(void* const* d_in, const int* in_sizes, int n_in,
                              void* d_out, int out_size, void* d_ws, size_t ws_size,
                              hipStream_t stream) {
  const float* x  = (const float*)d_in[0];
  const int* ei   = (const int*)d_in[1];
  const float* Wg = (const float*)d_in[2];
  const float* bg = (const float*)d_in[3];
  const float* Wa = (const float*)d_in[4];
  const float* ba = (const float*)d_in[5];
  const float* Wr = (const float*)d_in[6];
  const float* br = (const float*)d_in[7];
  float* out = (float*)d_out;     // fp32 output (reference dtype)

  const int N = in_sizes[0] / DIN;
  const int E = in_sizes[1] / 2;

  char* p = (char*)d_ws;
  auto alloc = [&](size_t bytes) {
    char* r = p;
    p += (bytes + 255) & ~(size_t)255;
    return r;
  };
  float* Dws    = (float*)alloc(256);
  float* colsum = (float*)alloc(128 * 4);
  float* VtZ    = (float*)alloc(4096 * 4);
  int*   degc   = (int*)alloc((size_t)N * 4);
  float* dinv   = (float*)alloc((size_t)N * 4);
  int*   offs   = (int*)alloc((size_t)(N + 1) * 4);
  int*   cursor = (int*)alloc((size_t)N * 4);
  int*   csr_s  = (int*)alloc((size_t)E * 4);
  float* csr_n  = (float*)alloc((size_t)E * 4);
  ushort_t* hs  = (ushort_t*)alloc((size_t)N * DOUT * 2);   // bf16 x@Wg
  ushort_t* t   = (ushort_t*)alloc((size_t)N * TCOLS * 2);  // bf16 relu(x@Wa+ba)
  (void)ws_size; (void)n_in; (void)out_size;

  const int GN = (N + 255) / 256;
  const int GE = (E + 255) / 256;

  k_init<<<GN, 256, 0, stream>>>(degc, VtZ, colsum, N);
  k_deg<<<GE, 256, 0, stream>>>(ei, degc, E);
  k_scan<<<1, 1024, 0, stream>>>(degc, offs, dinv, cursor, N);
  k_scatter<<<GE, 256, 0, stream>>>(ei, offs, cursor, dinv, csr_s, csr_n, E);
  k_gemm1<<<dim3(6, (N + 63) / 64), 256, 0, stream>>>(x, Wg, Wa, ba, hs, t, N);
  k_red<<<256, 256, 0, stream>>>(t, VtZ, colsum, N);
  k_d<<<1, 64, 0, stream>>>(colsum, Dws, N);
  k_final<<<(N + 31) / 32, 256, 0, stream>>>(hs, t, offs, csr_s, csr_n, dinv, VtZ, Dws,
                                             bg, Wr, br, out, N);
}

// Round 7
// 1129.183 us; speedup vs baseline: 1.2352x; 1.2352x over previous
//
#include <hip/hip_runtime.h>

// GCN + low-rank global attention (LRGA), N=100k, E=1.6M, D=128, K=64.
// Inputs fp32 + int32 edge_index; OUTPUT fp32.
// Intermediates h (x@Wg), t (relu(x@Wa+ba)), x_local stored bf16 in workspace.
#define DIN   128
#define DOUT  128
#define KR    64
#define TCOLS 256   // 4*K

typedef unsigned short ushort_t;

__device__ __forceinline__ float bf2f(unsigned short u) {
  return __uint_as_float(((unsigned int)u) << 16);
}
__device__ __forceinline__ unsigned short f2bf(float f) {
  unsigned int b = __float_as_uint(f);
  b = b + 0x7FFFu + ((b >> 16) & 1u);
  return (unsigned short)(b >> 16);
}

// ---------------------------------------------------------------- init
__global__ __launch_bounds__(256) void k_init(int* __restrict__ degc, float* __restrict__ VtZ,
                                              float* __restrict__ colsum, int N) {
  int i = blockIdx.x * 256 + threadIdx.x;
  if (i < N) degc[i] = 1;            // self-loop gives deg >= 1
  if (i < 4096) VtZ[i] = 0.f;
  if (i < 128) colsum[i] = 0.f;
}

// ---------------------------------------------------------------- degree (in-degree via dst row)
__global__ __launch_bounds__(256) void k_deg(const int* __restrict__ ei, int* __restrict__ degc, int E) {
  int e = blockIdx.x * 256 + threadIdx.x;
  if (e < E) atomicAdd(&degc[ei[E + e]], 1);
}

// ---------------------------------------------------------------- single-block scan:
// offs = exclusive prefix of (degc-1); offs[N] = E; dinv = rsqrt(degc); cursor = 0.
__global__ __launch_bounds__(1024) void k_scan(const int* __restrict__ degc, int* __restrict__ offs,
                                               float* __restrict__ dinv, int* __restrict__ cursor, int N) {
  __shared__ int s[1024];
  int tid = threadIdx.x;
  int CH = (N + 1023) >> 10;
  int i0 = tid * CH;
  int i1 = min(i0 + CH, N);
  int tsum = 0;
  for (int i = i0; i < i1; ++i) tsum += degc[i] - 1;
  s[tid] = tsum;
  __syncthreads();
  for (int off = 1; off < 1024; off <<= 1) {
    int v = (tid >= off) ? s[tid - off] : 0;
    __syncthreads();
    s[tid] += v;
    __syncthreads();
  }
  int run = s[tid] - tsum;
  for (int i = i0; i < i1; ++i) {
    offs[i] = run;
    run += degc[i] - 1;
    dinv[i] = rsqrtf((float)degc[i]);
    cursor[i] = 0;
  }
  if (tid == 0) offs[N] = s[1023];
}

// ---------------------------------------------------------------- CSR scatter: (src, norm) packed int2
__global__ __launch_bounds__(256) void k_scatter(const int* __restrict__ ei, const int* __restrict__ offs,
                                                 int* __restrict__ cursor, const float* __restrict__ dinv,
                                                 int2* __restrict__ csr, int E) {
  int e = blockIdx.x * 256 + threadIdx.x;
  if (e < E) {
    int s = ei[e];          // src
    int d = ei[E + e];      // dst
    int pos = atomicAdd(&cursor[d], 1);
    int2 q;
    q.x = s;
    q.y = __float_as_int(dinv[s] * dinv[d]);
    csr[offs[d] + pos] = q;
  }
}

// ---------------------------------------------------------------- fused GEMM: h = x@Wg (bf16) ; t = relu(x@Wa + ba) (bf16)
__global__ __launch_bounds__(256) void k_gemm1(const float* __restrict__ x,
                                               const float* __restrict__ Wg,
                                               const float* __restrict__ Wa,
                                               const float* __restrict__ ba,
                                               ushort_t* __restrict__ hs, ushort_t* __restrict__ t, int N) {
  __shared__ float xS[64 * 68];   // [row][k] stride 68
  __shared__ float wS[64 * 68];   // [k][col] stride 68
  int tid = threadIdx.x;
  int row0 = blockIdx.y * 64;
  int cbase = blockIdx.x * 64;
  int tc = tid & 15, tr = tid >> 4;
  float acc[4][4] = {};
  for (int kc = 0; kc < 2; ++kc) {
    for (int idx = tid; idx < 64 * 16; idx += 256) {
      int r = idx >> 4, c4 = idx & 15;
      int row = row0 + r;
      float4 v = (row < N) ? *(const float4*)&x[(size_t)row * DIN + kc * 64 + c4 * 4]
                           : make_float4(0.f, 0.f, 0.f, 0.f);
      *(float4*)&xS[r * 68 + c4 * 4] = v;
    }
    if (cbase < DOUT) {
      for (int idx = tid; idx < 64 * 16; idx += 256) {
        int k = idx >> 4, c4 = idx & 15;
        float4 v = *(const float4*)&Wg[(size_t)(kc * 64 + k) * DOUT + cbase + c4 * 4];
        *(float4*)&wS[k * 68 + c4 * 4] = v;
      }
    } else {
      for (int idx = tid; idx < 64 * 16; idx += 256) {
        int k = idx >> 4, c4 = idx & 15;
        float4 v = *(const float4*)&Wa[(size_t)(kc * 64 + k) * TCOLS + (cbase - DOUT) + c4 * 4];
        *(float4*)&wS[k * 68 + c4 * 4] = v;
      }
    }
    __syncthreads();
#pragma unroll
    for (int kv = 0; kv < 16; ++kv) {
      float xv[4][4], wv[4][4];
#pragma unroll
      for (int i = 0; i < 4; ++i) {
        float4 v = *(const float4*)&xS[(tr * 4 + i) * 68 + kv * 4];
        xv[i][0] = v.x; xv[i][1] = v.y; xv[i][2] = v.z; xv[i][3] = v.w;
      }
#pragma unroll
      for (int kk = 0; kk < 4; ++kk) {
        float4 v = *(const float4*)&wS[(kv * 4 + kk) * 68 + tc * 4];
        wv[kk][0] = v.x; wv[kk][1] = v.y; wv[kk][2] = v.z; wv[kk][3] = v.w;
      }
#pragma unroll
      for (int i = 0; i < 4; ++i)
#pragma unroll
        for (int kk = 0; kk < 4; ++kk) {
          acc[i][0] += xv[i][kk] * wv[kk][0];
          acc[i][1] += xv[i][kk] * wv[kk][1];
          acc[i][2] += xv[i][kk] * wv[kk][2];
          acc[i][3] += xv[i][kk] * wv[kk][3];
        }
    }
    __syncthreads();
  }
  int gc0 = cbase + tc * 4;
  if (gc0 < DOUT) {
#pragma unroll
    for (int i = 0; i < 4; ++i) {
      int row = row0 + tr * 4 + i;
      if (row < N) {
        ushort4 o;
        o.x = f2bf(acc[i][0]); o.y = f2bf(acc[i][1]);
        o.z = f2bf(acc[i][2]); o.w = f2bf(acc[i][3]);
        *(ushort4*)&hs[(size_t)row * DOUT + gc0] = o;
      }
    }
  } else {
    int ca0 = gc0 - DOUT;
    float bav[4];
#pragma unroll
    for (int q = 0; q < 4; ++q) bav[q] = ba[ca0 + q];
#pragma unroll
    for (int i = 0; i < 4; ++i) {
      int row = row0 + tr * 4 + i;
      if (row < N) {
        ushort4 o;
        o.x = f2bf(fmaxf(acc[i][0] + bav[0], 0.f));
        o.y = f2bf(fmaxf(acc[i][1] + bav[1], 0.f));
        o.z = f2bf(fmaxf(acc[i][2] + bav[2], 0.f));
        o.w = f2bf(fmaxf(acc[i][3] + bav[3], 0.f));
        *(ushort4*)&t[(size_t)row * TCOLS + ca0] = o;
      }
    }
  }
}

// ---------------------------------------------------------------- VtZ (64x64) + colsum(U),colsum(V)
__global__ __launch_bounds__(256) void k_red(const ushort_t* __restrict__ t, float* __restrict__ VtZ,
                                             float* __restrict__ colsum, int N) {
  __shared__ float uvz[16 * 192];   // cols 0..191 of t (U,V,Z)
  int tid = threadIdx.x;
  int RB = (N + gridDim.x - 1) / gridDim.x;
  int row0 = blockIdx.x * RB;
  int rowend = min(row0 + RB, N);
  int k = tid >> 2;
  int l0 = (tid & 3) * 16;
  float acc[16] = {};
  float cs = 0.f;
  for (int r0 = row0; r0 < rowend; r0 += 16) {
    for (int idx = tid; idx < 16 * 48; idx += 256) {
      int r = idx / 48, c4 = idx - r * 48;
      int row = r0 + r;
      float4 f;
      if (row < rowend) {
        ushort4 u = ((const ushort4*)&t[(size_t)row * TCOLS])[c4];
        f = make_float4(bf2f(u.x), bf2f(u.y), bf2f(u.z), bf2f(u.w));
      } else {
        f = make_float4(0.f, 0.f, 0.f, 0.f);
      }
      *(float4*)&uvz[r * 192 + c4 * 4] = f;
    }
    __syncthreads();
#pragma unroll
    for (int r = 0; r < 16; ++r) {
      float vk = uvz[r * 192 + 64 + k];
      const float4* zp = (const float4*)&uvz[r * 192 + 128 + l0];
#pragma unroll
      for (int q = 0; q < 4; ++q) {
        float4 z = zp[q];
        acc[q * 4 + 0] += vk * z.x;
        acc[q * 4 + 1] += vk * z.y;
        acc[q * 4 + 2] += vk * z.z;
        acc[q * 4 + 3] += vk * z.w;
      }
    }
    if (tid < 128) {
#pragma unroll
      for (int r = 0; r < 16; ++r) cs += uvz[r * 192 + tid];
    }
    __syncthreads();
  }
#pragma unroll
  for (int q = 0; q < 16; ++q) atomicAdd(&VtZ[k * 64 + l0 + q], acc[q]);
  if (tid < 128) atomicAdd(&colsum[tid], cs);
}

// ---------------------------------------------------------------- D = N / dot(colsumU, colsumV)
__global__ __launch_bounds__(64) void k_d(const float* __restrict__ colsum, float* __restrict__ Dws, int N) {
  __shared__ float s[64];
  int k = threadIdx.x;
  s[k] = colsum[k] * colsum[64 + k];
  __syncthreads();
  for (int off = 32; off > 0; off >>= 1) {
    if (k < off) s[k] += s[k + off];
    __syncthreads();
  }
  if (k == 0) {
    float p = s[0];
    Dws[0] = (p != 0.f) ? ((float)N / p) : 0.f;
  }
}

// ---------------------------------------------------------------- CSR gather-aggregate: x_local = relu(agg + b_gcn), bf16.
// No LDS -> high occupancy. 1 wave per node, lane covers 2 columns, ILP-4 over edges.
__global__ __launch_bounds__(256) void k_aggn(const ushort_t* __restrict__ hs, const int2* __restrict__ csr,
                                              const int* __restrict__ offs, const float* __restrict__ dinv,
                                              const float* __restrict__ bg,
                                              ushort_t* __restrict__ xl, int N) {
  int node = blockIdx.x * 4 + (threadIdx.x >> 6);
  int lane = threadIdx.x & 63;
  if (node >= N) return;
  int c2 = 2 * lane;
  float dn = dinv[node];
  ushort2 u = *(const ushort2*)&hs[(size_t)node * DOUT + c2];
  float a0 = dn * dn * bf2f(u.x);
  float a1 = dn * dn * bf2f(u.y);
  int e = offs[node], e1 = offs[node + 1];
  for (; e + 4 <= e1; e += 4) {
    int2 q0 = csr[e], q1 = csr[e + 1], q2 = csr[e + 2], q3 = csr[e + 3];
    ushort2 r0 = *(const ushort2*)&hs[(size_t)q0.x * DOUT + c2];
    ushort2 r1 = *(const ushort2*)&hs[(size_t)q1.x * DOUT + c2];
    ushort2 r2 = *(const ushort2*)&hs[(size_t)q2.x * DOUT + c2];
    ushort2 r3 = *(const ushort2*)&hs[(size_t)q3.x * DOUT + c2];
    float n0 = __int_as_float(q0.y), n1 = __int_as_float(q1.y);
    float n2 = __int_as_float(q2.y), n3 = __int_as_float(q3.y);
    a0 += n0 * bf2f(r0.x) + n1 * bf2f(r1.x) + n2 * bf2f(r2.x) + n3 * bf2f(r3.x);
    a1 += n0 * bf2f(r0.y) + n1 * bf2f(r1.y) + n2 * bf2f(r2.y) + n3 * bf2f(r3.y);
  }
  for (; e < e1; ++e) {
    int2 q = csr[e];
    ushort2 r = *(const ushort2*)&hs[(size_t)q.x * DOUT + c2];
    float n0 = __int_as_float(q.y);
    a0 += n0 * bf2f(r.x);
    a1 += n0 * bf2f(r.y);
  }
  ushort2 o;
  o.x = f2bf(fmaxf(a0 + bg[c2], 0.f));
  o.y = f2bf(fmaxf(a1 + bg[c2 + 1], 0.f));
  *(ushort2*)&xl[(size_t)node * DOUT + c2] = o;
}

// ---------------------------------------------------------------- out: y = [x_local | U@VtZ*D | T]; out = y@W_red + b_red (fp32)
__global__ __launch_bounds__(256) void k_out(const ushort_t* __restrict__ xl, const ushort_t* __restrict__ t,
                                             const float* __restrict__ VtZg, const float* __restrict__ Dws,
                                             const float* __restrict__ Wr, const float* __restrict__ br,
                                             float* __restrict__ out, int N) {
  __shared__ float yS[32 * 260];    // [node][256 + pad]
  __shared__ float vtzS[4096];
  int tid = threadIdx.x;
  for (int idx = tid; idx < 4096; idx += 256) vtzS[idx] = VtZg[idx];
  for (int idx = tid; idx < 32 * 260; idx += 256) yS[idx] = 0.f;
  __syncthreads();
  int lane = tid & 63;
  int wave = tid >> 6;
  float Dv = Dws[0];
  int nb = blockIdx.x * 32;
  int c2 = 2 * lane;
  for (int p = 0; p < 8; ++p) {
    int ln = wave * 8 + p;
    int node = nb + ln;
    if (node < N) {
      ushort2 u = *(const ushort2*)&xl[(size_t)node * DOUT + c2];
      yS[ln * 260 + c2]     = bf2f(u.x);
      yS[ln * 260 + c2 + 1] = bf2f(u.y);
      const ushort_t* Urow = &t[(size_t)node * TCOLS];
      float r = 0.f;
#pragma unroll 16
      for (int k = 0; k < 64; ++k) r += bf2f(Urow[k]) * vtzS[k * 64 + lane];
      yS[ln * 260 + 128 + lane] = r * Dv;
      yS[ln * 260 + 192 + lane] = bf2f(Urow[192 + lane]);
    }
  }
  __syncthreads();
  // out[32 x 128] = y[32 x 256] @ W_red[256 x 128] + b_red
  int tc = tid & 31, tr = tid >> 5;
  int c0 = tc * 4, m0 = tr * 4;
  float brv[4];
#pragma unroll
  for (int q = 0; q < 4; ++q) brv[q] = br[c0 + q];
  float acc2[4][4] = {};
  for (int qc = 0; qc < 64; ++qc) {
    float yv[4][4], wv[4][4];
#pragma unroll
    for (int i = 0; i < 4; ++i) {
      float4 v = *(const float4*)&yS[(m0 + i) * 260 + qc * 4];
      yv[i][0] = v.x; yv[i][1] = v.y; yv[i][2] = v.z; yv[i][3] = v.w;
    }
#pragma unroll
    for (int kk = 0; kk < 4; ++kk) {
      float4 v = *(const float4*)&Wr[(size_t)(qc * 4 + kk) * DOUT + c0];
      wv[kk][0] = v.x; wv[kk][1] = v.y; wv[kk][2] = v.z; wv[kk][3] = v.w;
    }
#pragma unroll
    for (int i = 0; i < 4; ++i)
#pragma unroll
      for (int kk = 0; kk < 4; ++kk) {
        acc2[i][0] += yv[i][kk] * wv[kk][0];
        acc2[i][1] += yv[i][kk] * wv[kk][1];
        acc2[i][2] += yv[i][kk] * wv[kk][2];
        acc2[i][3] += yv[i][kk] * wv[kk][3];
      }
  }
#pragma unroll
  for (int i = 0; i < 4; ++i) {
    int node = nb + m0 + i;
    if (node < N) {
      float4 o = make_float4(acc2[i][0] + brv[0], acc2[i][1] + brv[1],
                             acc2[i][2] + brv[2], acc2[i][3] + brv[3]);
      *(float4*)&out[(size_t)node * DOUT + c0] = o;
    }
  }
}

// ---------------------------------------------------------------- launch
extern "C" void kernel_launch(void* const* d_in, const int* in_sizes, int n_in,
                              void* d_out, int out_size, void* d_ws, size_t ws_size,
                              hipStream_t stream) {
  const float* x  = (const float*)d_in[0];
  const int* ei   = (const int*)d_in[1];
  const float* Wg = (const float*)d_in[2];
  const float* bg = (const float*)d_in[3];
  const float* Wa = (const float*)d_in[4];
  const float* ba = (const float*)d_in[5];
  const float* Wr = (const float*)d_in[6];
  const float* br = (const float*)d_in[7];
  float* out = (float*)d_out;     // fp32 output

  const int N = in_sizes[0] / DIN;
  const int E = in_sizes[1] / 2;

  char* p = (char*)d_ws;
  auto alloc = [&](size_t bytes) {
    char* r = p;
    p += (bytes + 255) & ~(size_t)255;
    return r;
  };
  float* Dws    = (float*)alloc(256);
  float* colsum = (float*)alloc(128 * 4);
  float* VtZ    = (float*)alloc(4096 * 4);
  int*   degc   = (int*)alloc((size_t)N * 4);
  float* dinv   = (float*)alloc((size_t)N * 4);
  int*   offs   = (int*)alloc((size_t)(N + 1) * 4);
  int*   cursor = (int*)alloc((size_t)N * 4);
  int2*  csr    = (int2*)alloc((size_t)E * 8);              // (src, norm) per edge
  ushort_t* hs  = (ushort_t*)alloc((size_t)N * DOUT * 2);   // bf16 x@Wg
  ushort_t* t   = (ushort_t*)alloc((size_t)N * TCOLS * 2);  // bf16 relu(x@Wa+ba)
  ushort_t* xl  = (ushort_t*)alloc((size_t)N * DOUT * 2);   // bf16 x_local
  (void)ws_size; (void)n_in; (void)out_size;

  const int GN = (N + 255) / 256;
  const int GE = (E + 255) / 256;

  k_init<<<GN, 256, 0, stream>>>(degc, VtZ, colsum, N);
  k_deg<<<GE, 256, 0, stream>>>(ei, degc, E);
  k_scan<<<1, 1024, 0, stream>>>(degc, offs, dinv, cursor, N);
  k_scatter<<<GE, 256, 0, stream>>>(ei, offs, cursor, dinv, csr, E);
  k_gemm1<<<dim3(6, (N + 63) / 64), 256, 0, stream>>>(x, Wg, Wa, ba, hs, t, N);
  k_red<<<256, 256, 0, stream>>>(t, VtZ, colsum, N);
  k_d<<<1, 64, 0, stream>>>(colsum, Dws, N);
  k_aggn<<<(N + 3) / 4, 256, 0, stream>>>(hs, csr, offs, dinv, bg, xl, N);
  k_out<<<(N + 31) / 32, 256, 0, stream>>>(xl, t, VtZ, Dws, Wr, br, out, N);
}

// Round 8
// 864.731 us; speedup vs baseline: 1.6130x; 1.3058x over previous
//
#include <hip/hip_runtime.h>

// GCN + low-rank global attention (LRGA), N=100k, E=1.6M, D=128, K=64.
// Inputs fp32 + int32 edge_index; OUTPUT fp32.
// Intermediates h (x@Wg), t (relu(x@Wa+ba)), x_local stored bf16 in workspace.
#define DIN   128
#define DOUT  128
#define KR    64
#define TCOLS 256   // 4*K

typedef unsigned short ushort_t;

__device__ __forceinline__ float bf2f(unsigned short u) {
  return __uint_as_float(((unsigned int)u) << 16);
}
__device__ __forceinline__ unsigned short f2bf(float f) {
  unsigned int b = __float_as_uint(f);
  b = b + 0x7FFFu + ((b >> 16) & 1u);
  return (unsigned short)(b >> 16);
}

// ---------------------------------------------------------------- init
__global__ __launch_bounds__(256) void k_init(int* __restrict__ degc, float* __restrict__ VtZ,
                                              float* __restrict__ colsum, int N) {
  int i = blockIdx.x * 256 + threadIdx.x;
  if (i < N) degc[i] = 1;            // self-loop gives deg >= 1
  if (i < 4096) VtZ[i] = 0.f;
  if (i < 128) colsum[i] = 0.f;
}

// ---------------------------------------------------------------- degree (in-degree via dst row)
__global__ __launch_bounds__(256) void k_deg(const int* __restrict__ ei, int* __restrict__ degc, int E) {
  int e = blockIdx.x * 256 + threadIdx.x;
  if (e < E) atomicAdd(&degc[ei[E + e]], 1);
}

// ---------------------------------------------------------------- hierarchical scan, stage 1:
// per-block exclusive scan of (degc-1) over 1024-element tiles; block sums out.
__global__ __launch_bounds__(256) void k_scan1(const int* __restrict__ degc, int* __restrict__ offs,
                                               int* __restrict__ bsums, int N) {
  __shared__ int s[256];
  int tid = threadIdx.x;
  int base = blockIdx.x * 1024 + tid * 4;
  int c[4], e[4];
#pragma unroll
  for (int q = 0; q < 4; ++q) c[q] = (base + q < N) ? (degc[base + q] - 1) : 0;
  e[0] = 0; e[1] = c[0]; e[2] = e[1] + c[1]; e[3] = e[2] + c[2];
  int tsum = e[3] + c[3];
  s[tid] = tsum; __syncthreads();
  for (int off = 1; off < 256; off <<= 1) {
    int v = (tid >= off) ? s[tid - off] : 0;
    __syncthreads();
    s[tid] += v;
    __syncthreads();
  }
  int tb = s[tid] - tsum;
#pragma unroll
  for (int q = 0; q < 4; ++q) if (base + q < N) offs[base + q] = tb + e[q];
  if (tid == 255) bsums[blockIdx.x] = s[255];
}

// stage 2: exclusive scan of block sums (NBLK <= 128)
__global__ __launch_bounds__(128) void k_scan2(const int* __restrict__ bsums, int* __restrict__ boff,
                                               int* __restrict__ offs, int NBLK, int N) {
  __shared__ int s[128];
  int tid = threadIdx.x;
  int v = (tid < NBLK) ? bsums[tid] : 0;
  s[tid] = v; __syncthreads();
  for (int off = 1; off < 128; off <<= 1) {
    int u = (tid >= off) ? s[tid - off] : 0;
    __syncthreads();
    s[tid] += u;
    __syncthreads();
  }
  boff[tid] = s[tid] - v;
  if (tid == 127) offs[N] = s[127];   // total = E
}

// stage 3: add block offsets; dinv = rsqrt(deg); cursor = 0
__global__ __launch_bounds__(256) void k_scan3(int* __restrict__ offs, const int* __restrict__ boff,
                                               const int* __restrict__ degc, float* __restrict__ dinv,
                                               int* __restrict__ cursor, int N) {
  int i = blockIdx.x * 256 + threadIdx.x;
  if (i < N) {
    offs[i] += boff[i >> 10];
    dinv[i] = rsqrtf((float)degc[i]);
    cursor[i] = 0;
  }
}

// ---------------------------------------------------------------- CSR scatter: (src, norm) packed int2
__global__ __launch_bounds__(256) void k_scatter(const int* __restrict__ ei, const int* __restrict__ offs,
                                                 int* __restrict__ cursor, const float* __restrict__ dinv,
                                                 int2* __restrict__ csr, int E) {
  int e = blockIdx.x * 256 + threadIdx.x;
  if (e < E) {
    int s = ei[e];          // src
    int d = ei[E + e];      // dst
    int pos = atomicAdd(&cursor[d], 1);
    int2 q;
    q.x = s;
    q.y = __float_as_int(dinv[s] * dinv[d]);
    csr[offs[d] + pos] = q;
  }
}

// ---------------------------------------------------------------- fused GEMM: h = x@Wg (bf16) ; t = relu(x@Wa + ba) (bf16)
__global__ __launch_bounds__(256) void k_gemm1(const float* __restrict__ x,
                                               const float* __restrict__ Wg,
                                               const float* __restrict__ Wa,
                                               const float* __restrict__ ba,
                                               ushort_t* __restrict__ hs, ushort_t* __restrict__ t, int N) {
  __shared__ float xS[64 * 68];   // [row][k] stride 68
  __shared__ float wS[64 * 68];   // [k][col] stride 68
  int tid = threadIdx.x;
  int row0 = blockIdx.y * 64;
  int cbase = blockIdx.x * 64;
  int tc = tid & 15, tr = tid >> 4;
  float acc[4][4] = {};
  for (int kc = 0; kc < 2; ++kc) {
    for (int idx = tid; idx < 64 * 16; idx += 256) {
      int r = idx >> 4, c4 = idx & 15;
      int row = row0 + r;
      float4 v = (row < N) ? *(const float4*)&x[(size_t)row * DIN + kc * 64 + c4 * 4]
                           : make_float4(0.f, 0.f, 0.f, 0.f);
      *(float4*)&xS[r * 68 + c4 * 4] = v;
    }
    if (cbase < DOUT) {
      for (int idx = tid; idx < 64 * 16; idx += 256) {
        int k = idx >> 4, c4 = idx & 15;
        float4 v = *(const float4*)&Wg[(size_t)(kc * 64 + k) * DOUT + cbase + c4 * 4];
        *(float4*)&wS[k * 68 + c4 * 4] = v;
      }
    } else {
      for (int idx = tid; idx < 64 * 16; idx += 256) {
        int k = idx >> 4, c4 = idx & 15;
        float4 v = *(const float4*)&Wa[(size_t)(kc * 64 + k) * TCOLS + (cbase - DOUT) + c4 * 4];
        *(float4*)&wS[k * 68 + c4 * 4] = v;
      }
    }
    __syncthreads();
#pragma unroll
    for (int kv = 0; kv < 16; ++kv) {
      float xv[4][4], wv[4][4];
#pragma unroll
      for (int i = 0; i < 4; ++i) {
        float4 v = *(const float4*)&xS[(tr * 4 + i) * 68 + kv * 4];
        xv[i][0] = v.x; xv[i][1] = v.y; xv[i][2] = v.z; xv[i][3] = v.w;
      }
#pragma unroll
      for (int kk = 0; kk < 4; ++kk) {
        float4 v = *(const float4*)&wS[(kv * 4 + kk) * 68 + tc * 4];
        wv[kk][0] = v.x; wv[kk][1] = v.y; wv[kk][2] = v.z; wv[kk][3] = v.w;
      }
#pragma unroll
      for (int i = 0; i < 4; ++i)
#pragma unroll
        for (int kk = 0; kk < 4; ++kk) {
          acc[i][0] += xv[i][kk] * wv[kk][0];
          acc[i][1] += xv[i][kk] * wv[kk][1];
          acc[i][2] += xv[i][kk] * wv[kk][2];
          acc[i][3] += xv[i][kk] * wv[kk][3];
        }
    }
    __syncthreads();
  }
  int gc0 = cbase + tc * 4;
  if (gc0 < DOUT) {
#pragma unroll
    for (int i = 0; i < 4; ++i) {
      int row = row0 + tr * 4 + i;
      if (row < N) {
        ushort4 o;
        o.x = f2bf(acc[i][0]); o.y = f2bf(acc[i][1]);
        o.z = f2bf(acc[i][2]); o.w = f2bf(acc[i][3]);
        *(ushort4*)&hs[(size_t)row * DOUT + gc0] = o;
      }
    }
  } else {
    int ca0 = gc0 - DOUT;
    float bav[4];
#pragma unroll
    for (int q = 0; q < 4; ++q) bav[q] = ba[ca0 + q];
#pragma unroll
    for (int i = 0; i < 4; ++i) {
      int row = row0 + tr * 4 + i;
      if (row < N) {
        ushort4 o;
        o.x = f2bf(fmaxf(acc[i][0] + bav[0], 0.f));
        o.y = f2bf(fmaxf(acc[i][1] + bav[1], 0.f));
        o.z = f2bf(fmaxf(acc[i][2] + bav[2], 0.f));
        o.w = f2bf(fmaxf(acc[i][3] + bav[3], 0.f));
        *(ushort4*)&t[(size_t)row * TCOLS + ca0] = o;
      }
    }
  }
}

// ---------------------------------------------------------------- VtZ (64x64) + colsum(U),colsum(V)
__global__ __launch_bounds__(256) void k_red(const ushort_t* __restrict__ t, float* __restrict__ VtZ,
                                             float* __restrict__ colsum, int N) {
  __shared__ float uvz[16 * 192];   // cols 0..191 of t (U,V,Z)
  int tid = threadIdx.x;
  int RB = (N + gridDim.x - 1) / gridDim.x;
  int row0 = blockIdx.x * RB;
  int rowend = min(row0 + RB, N);
  int k = tid >> 2;
  int l0 = (tid & 3) * 16;
  float acc[16] = {};
  float cs = 0.f;
  for (int r0 = row0; r0 < rowend; r0 += 16) {
    for (int idx = tid; idx < 16 * 48; idx += 256) {
      int r = idx / 48, c4 = idx - r * 48;
      int row = r0 + r;
      float4 f;
      if (row < rowend) {
        ushort4 u = ((const ushort4*)&t[(size_t)row * TCOLS])[c4];
        f = make_float4(bf2f(u.x), bf2f(u.y), bf2f(u.z), bf2f(u.w));
      } else {
        f = make_float4(0.f, 0.f, 0.f, 0.f);
      }
      *(float4*)&uvz[r * 192 + c4 * 4] = f;
    }
    __syncthreads();
#pragma unroll
    for (int r = 0; r < 16; ++r) {
      float vk = uvz[r * 192 + 64 + k];
      const float4* zp = (const float4*)&uvz[r * 192 + 128 + l0];
#pragma unroll
      for (int q = 0; q < 4; ++q) {
        float4 z = zp[q];
        acc[q * 4 + 0] += vk * z.x;
        acc[q * 4 + 1] += vk * z.y;
        acc[q * 4 + 2] += vk * z.z;
        acc[q * 4 + 3] += vk * z.w;
      }
    }
    if (tid < 128) {
#pragma unroll
      for (int r = 0; r < 16; ++r) cs += uvz[r * 192 + tid];
    }
    __syncthreads();
  }
#pragma unroll
  for (int q = 0; q < 16; ++q) atomicAdd(&VtZ[k * 64 + l0 + q], acc[q]);
  if (tid < 128) atomicAdd(&colsum[tid], cs);
}

// ---------------------------------------------------------------- D = N / dot(colsumU, colsumV)
__global__ __launch_bounds__(64) void k_d(const float* __restrict__ colsum, float* __restrict__ Dws, int N) {
  __shared__ float s[64];
  int k = threadIdx.x;
  s[k] = colsum[k] * colsum[64 + k];
  __syncthreads();
  for (int off = 32; off > 0; off >>= 1) {
    if (k < off) s[k] += s[k + off];
    __syncthreads();
  }
  if (k == 0) {
    float p = s[0];
    Dws[0] = (p != 0.f) ? ((float)N / p) : 0.f;
  }
}

// ---------------------------------------------------------------- CSR gather-aggregate: x_local = relu(agg + b_gcn), bf16.
// No LDS -> high occupancy. 1 wave per node, lane covers 2 columns, ILP-4 over edges.
__global__ __launch_bounds__(256) void k_aggn(const ushort_t* __restrict__ hs, const int2* __restrict__ csr,
                                              const int* __restrict__ offs, const float* __restrict__ dinv,
                                              const float* __restrict__ bg,
                                              ushort_t* __restrict__ xl, int N) {
  int node = blockIdx.x * 4 + (threadIdx.x >> 6);
  int lane = threadIdx.x & 63;
  if (node >= N) return;
  int c2 = 2 * lane;
  float dn = dinv[node];
  ushort2 u = *(const ushort2*)&hs[(size_t)node * DOUT + c2];
  float a0 = dn * dn * bf2f(u.x);
  float a1 = dn * dn * bf2f(u.y);
  int e = offs[node], e1 = offs[node + 1];
  for (; e + 4 <= e1; e += 4) {
    int2 q0 = csr[e], q1 = csr[e + 1], q2 = csr[e + 2], q3 = csr[e + 3];
    ushort2 r0 = *(const ushort2*)&hs[(size_t)q0.x * DOUT + c2];
    ushort2 r1 = *(const ushort2*)&hs[(size_t)q1.x * DOUT + c2];
    ushort2 r2 = *(const ushort2*)&hs[(size_t)q2.x * DOUT + c2];
    ushort2 r3 = *(const ushort2*)&hs[(size_t)q3.x * DOUT + c2];
    float n0 = __int_as_float(q0.y), n1 = __int_as_float(q1.y);
    float n2 = __int_as_float(q2.y), n3 = __int_as_float(q3.y);
    a0 += n0 * bf2f(r0.x) + n1 * bf2f(r1.x) + n2 * bf2f(r2.x) + n3 * bf2f(r3.x);
    a1 += n0 * bf2f(r0.y) + n1 * bf2f(r1.y) + n2 * bf2f(r2.y) + n3 * bf2f(r3.y);
  }
  for (; e < e1; ++e) {
    int2 q = csr[e];
    ushort2 r = *(const ushort2*)&hs[(size_t)q.x * DOUT + c2];
    float n0 = __int_as_float(q.y);
    a0 += n0 * bf2f(r.x);
    a1 += n0 * bf2f(r.y);
  }
  ushort2 o;
  o.x = f2bf(fmaxf(a0 + bg[c2], 0.f));
  o.y = f2bf(fmaxf(a1 + bg[c2 + 1], 0.f));
  *(ushort2*)&xl[(size_t)node * DOUT + c2] = o;
}

// ---------------------------------------------------------------- out: y = [x_local | U@VtZ*D | T]; out = y@W_red + b_red (fp32)
__global__ __launch_bounds__(256) void k_out(const ushort_t* __restrict__ xl, const ushort_t* __restrict__ t,
                                             const float* __restrict__ VtZg, const float* __restrict__ Dws,
                                             const float* __restrict__ Wr, const float* __restrict__ br,
                                             float* __restrict__ out, int N) {
  __shared__ float yS[32 * 260];    // [node][256 + pad]
  __shared__ float vtzS[4096];
  int tid = threadIdx.x;
  for (int idx = tid; idx < 4096; idx += 256) vtzS[idx] = VtZg[idx];
  for (int idx = tid; idx < 32 * 260; idx += 256) yS[idx] = 0.f;
  __syncthreads();
  int lane = tid & 63;
  int wave = tid >> 6;
  float Dv = Dws[0];
  int nb = blockIdx.x * 32;
  int c2 = 2 * lane;
  for (int p = 0; p < 8; ++p) {
    int ln = wave * 8 + p;
    int node = nb + ln;
    if (node < N) {
      ushort2 u = *(const ushort2*)&xl[(size_t)node * DOUT + c2];
      yS[ln * 260 + c2]     = bf2f(u.x);
      yS[ln * 260 + c2 + 1] = bf2f(u.y);
      const ushort_t* Urow = &t[(size_t)node * TCOLS];
      float r = 0.f;
#pragma unroll 16
      for (int k = 0; k < 64; ++k) r += bf2f(Urow[k]) * vtzS[k * 64 + lane];
      yS[ln * 260 + 128 + lane] = r * Dv;
      yS[ln * 260 + 192 + lane] = bf2f(Urow[192 + lane]);
    }
  }
  __syncthreads();
  // out[32 x 128] = y[32 x 256] @ W_red[256 x 128] + b_red
  int tc = tid & 31, tr = tid >> 5;
  int c0 = tc * 4, m0 = tr * 4;
  float brv[4];
#pragma unroll
  for (int q = 0; q < 4; ++q) brv[q] = br[c0 + q];
  float acc2[4][4] = {};
  for (int qc = 0; qc < 64; ++qc) {
    float yv[4][4], wv[4][4];
#pragma unroll
    for (int i = 0; i < 4; ++i) {
      float4 v = *(const float4*)&yS[(m0 + i) * 260 + qc * 4];
      yv[i][0] = v.x; yv[i][1] = v.y; yv[i][2] = v.z; yv[i][3] = v.w;
    }
#pragma unroll
    for (int kk = 0; kk < 4; ++kk) {
      float4 v = *(const float4*)&Wr[(size_t)(qc * 4 + kk) * DOUT + c0];
      wv[kk][0] = v.x; wv[kk][1] = v.y; wv[kk][2] = v.z; wv[kk][3] = v.w;
    }
#pragma unroll
    for (int i = 0; i < 4; ++i)
#pragma unroll
      for (int kk = 0; kk < 4; ++kk) {
        acc2[i][0] += yv[i][kk] * wv[kk][0];
        acc2[i][1] += yv[i][kk] * wv[kk][1];
        acc2[i][2] += yv[i][kk] * wv[kk][2];
        acc2[i][3] += yv[i][kk] * wv[kk][3];
      }
  }
#pragma unroll
  for (int i = 0; i < 4; ++i) {
    int node = nb + m0 + i;
    if (node < N) {
      float4 o = make_float4(acc2[i][0] + brv[0], acc2[i][1] + brv[1],
                             acc2[i][2] + brv[2], acc2[i][3] + brv[3]);
      *(float4*)&out[(size_t)node * DOUT + c0] = o;
    }
  }
}

// ---------------------------------------------------------------- launch
extern "C" void kernel_launch(void* const* d_in, const int* in_sizes, int n_in,
                              void* d_out, int out_size, void* d_ws, size_t ws_size,
                              hipStream_t stream) {
  const float* x  = (const float*)d_in[0];
  const int* ei   = (const int*)d_in[1];
  const float* Wg = (const float*)d_in[2];
  const float* bg = (const float*)d_in[3];
  const float* Wa = (const float*)d_in[4];
  const float* ba = (const float*)d_in[5];
  const float* Wr = (const float*)d_in[6];
  const float* br = (const float*)d_in[7];
  float* out = (float*)d_out;     // fp32 output

  const int N = in_sizes[0] / DIN;
  const int E = in_sizes[1] / 2;

  char* p = (char*)d_ws;
  auto alloc = [&](size_t bytes) {
    char* r = p;
    p += (bytes + 255) & ~(size_t)255;
    return r;
  };
  float* Dws    = (float*)alloc(256);
  float* colsum = (float*)alloc(128 * 4);
  float* VtZ    = (float*)alloc(4096 * 4);
  int*   bsums  = (int*)alloc(1024);
  int*   boff   = (int*)alloc(1024);
  int*   degc   = (int*)alloc((size_t)N * 4);
  float* dinv   = (float*)alloc((size_t)N * 4);
  int*   offs   = (int*)alloc((size_t)(N + 1) * 4);
  int*   cursor = (int*)alloc((size_t)N * 4);
  int2*  csr    = (int2*)alloc((size_t)E * 8);              // (src, norm) per edge
  ushort_t* hs  = (ushort_t*)alloc((size_t)N * DOUT * 2);   // bf16 x@Wg
  ushort_t* t   = (ushort_t*)alloc((size_t)N * TCOLS * 2);  // bf16 relu(x@Wa+ba)
  ushort_t* xl  = (ushort_t*)alloc((size_t)N * DOUT * 2);   // bf16 x_local
  (void)ws_size; (void)n_in; (void)out_size;

  const int GN = (N + 255) / 256;
  const int GE = (E + 255) / 256;
  const int NBLK = (N + 1023) / 1024;   // <= 128 for N <= 131072

  k_init<<<GN, 256, 0, stream>>>(degc, VtZ, colsum, N);
  k_deg<<<GE, 256, 0, stream>>>(ei, degc, E);
  k_scan1<<<NBLK, 256, 0, stream>>>(degc, offs, bsums, N);
  k_scan2<<<1, 128, 0, stream>>>(bsums, boff, offs, NBLK, N);
  k_scan3<<<GN, 256, 0, stream>>>(offs, boff, degc, dinv, cursor, N);
  k_scatter<<<GE, 256, 0, stream>>>(ei, offs, cursor, dinv, csr, E);
  k_gemm1<<<dim3(6, (N + 63) / 64), 256, 0, stream>>>(x, Wg, Wa, ba, hs, t, N);
  k_red<<<256, 256, 0, stream>>>(t, VtZ, colsum, N);
  k_d<<<1, 64, 0, stream>>>(colsum, Dws, N);
  k_aggn<<<(N + 3) / 4, 256, 0, stream>>>(hs, csr, offs, dinv, bg, xl, N);
  k_out<<<(N + 31) / 32, 256, 0, stream>>>(xl, t, VtZ, Dws, Wr, br, out, N);
}